// Round 2
// baseline (287.407 us; speedup 1.0000x reference)
//
#include <hip/hip_runtime.h>

// SO2Linear: out[n, M_out[e], c] += x[n, M_in[e], c] * weight[w_idx[e], c] * sign[e]
// L_MAX=6 -> 49 orders, 413 entries, 231 weights. N=2048, C=256.
// Entry tables are a deterministic function of L_MAX; generated at compile time.

#define LMAX 6
#define NORD 49            // (LMAX+1)^2
#define NENT 413
#define C4   64            // C/4 float4 lanes

struct Meta {
  unsigned packed[NENT];   // m_in | (w_idx<<8) | (sign_bit<<31), sorted by (i_out, i_in)
  int gstart[NORD + 1];    // entry range per i_out group
  int wbeg[5];             // group-range boundaries for the 4 waves of a block
};

constexpr Meta make_meta() {
  Meta m{};
  int io[NENT] = {}, ii[NENT] = {}, wi[NENT] = {}, sg[NENT] = {};
  int cnt = 0, widx = 0;
  for (int lo = 0; lo <= LMAX; ++lo) {
    for (int li = 0; li <= LMAX; ++li) {
      int mn = lo < li ? lo : li;
      for (int mw = -mn; mw <= mn; ++mw) {
        if (mw == 0) {
          io[cnt] = lo * lo + lo; ii[cnt] = li * li + li;
          wi[cnt] = widx; sg[cnt] = 0; ++cnt;
        } else {
          int a = mw > 0 ? mw : -mw;
          // pair (-|mw|, -mw): m_out < 0 -> sign +1
          io[cnt] = lo * lo + lo - a; ii[cnt] = li * li + li - mw;
          wi[cnt] = widx; sg[cnt] = 0; ++cnt;
          // pair (|mw|, mw): m_out > 0, sign -1 iff m_in = mw < 0
          io[cnt] = lo * lo + lo + a; ii[cnt] = li * li + li + mw;
          wi[cnt] = widx; sg[cnt] = (mw < 0) ? 1 : 0; ++cnt;
        }
        ++widx;
      }
    }
  }
  // cnt == 413, widx == 231. Sort by (i_out, i_in): keys unique -> bucket sort.
  int slot[NORD * NORD];
  for (int k = 0; k < NORD * NORD; ++k) slot[k] = -1;
  for (int e = 0; e < cnt; ++e) slot[io[e] * NORD + ii[e]] = e;
  int order[NENT] = {};
  int s = 0;
  for (int k = 0; k < NORD * NORD; ++k)
    if (slot[k] >= 0) order[s++] = slot[k];
  // group offsets per i_out
  int gc[NORD] = {};
  for (int e = 0; e < cnt; ++e) gc[io[e]]++;
  m.gstart[0] = 0;
  for (int g = 0; g < NORD; ++g) m.gstart[g + 1] = m.gstart[g] + gc[g];
  // packed metadata in sorted order
  for (int t = 0; t < cnt; ++t) {
    int e = order[t];
    m.packed[t] = (unsigned)ii[e] | ((unsigned)wi[e] << 8) | ((unsigned)sg[e] << 31);
  }
  // 4-way wave partition of groups, balanced by entry count (107/104/101/101)
  m.wbeg[0] = 0; m.wbeg[4] = NORD;
  for (int y = 1; y < 4; ++y) {
    int target = (cnt * y) / 4;
    int g = m.wbeg[y - 1] + 1;
    while (g < NORD && m.gstart[g] < target) ++g;
    if (g - 1 > m.wbeg[y - 1] &&
        (m.gstart[g] - target) > (target - m.gstart[g - 1])) --g;
    m.wbeg[y] = g;
  }
  return m;
}

__device__ constexpr Meta g_meta = make_meta();

__global__ __launch_bounds__(256) void so2_kernel(
    const float* __restrict__ x, const float* __restrict__ w,
    float* __restrict__ out) {
  // block = one n; 4 waves split the 49 output groups; lane = c/4 (float4).
  __shared__ float4 xs[NORD * C4];  // 50176 B -> 3 blocks/CU
  const int tid = threadIdx.x;
  const int n = blockIdx.x;

  // Stage x[n, :, :] into LDS, coalesced float4 (16 B/lane).
  const float4* __restrict__ xg =
      reinterpret_cast<const float4*>(x) + (size_t)n * (NORD * C4);
#pragma unroll
  for (int i = 0; i < 13; ++i) {
    int idx = tid + i * 256;
    if (idx < NORD * C4) xs[idx] = xg[idx];
  }
  __syncthreads();

  const int lane = tid & 63;
  const int yw = tid >> 6;
  const float4* __restrict__ wg = reinterpret_cast<const float4*>(w);
  float4* __restrict__ og =
      reinterpret_cast<float4*>(out) + (size_t)n * (NORD * C4);

  const int gbeg = g_meta.wbeg[yw];
  const int gend = g_meta.wbeg[yw + 1];
  for (int g = gbeg; g < gend; ++g) {
    float4 acc = make_float4(0.f, 0.f, 0.f, 0.f);
    const int e1 = g_meta.gstart[g + 1];
    for (int e = g_meta.gstart[g]; e < e1; ++e) {
      const unsigned p = g_meta.packed[e];       // wave-uniform -> scalar load
      const int mi = (int)(p & 255u);
      const int wix = (int)((p >> 8) & 0x3FFu);
      const unsigned sbit = p & 0x80000000u;     // fold sign via bit-XOR
      float4 xv = xs[mi * C4 + lane];            // LDS, conflict-free
      const float4 wv = wg[wix * C4 + lane];     // L2-resident (~236 KB total)
      xv.x = __uint_as_float(__float_as_uint(xv.x) ^ sbit);
      xv.y = __uint_as_float(__float_as_uint(xv.y) ^ sbit);
      xv.z = __uint_as_float(__float_as_uint(xv.z) ^ sbit);
      xv.w = __uint_as_float(__float_as_uint(xv.w) ^ sbit);
      acc.x = fmaf(xv.x, wv.x, acc.x);
      acc.y = fmaf(xv.y, wv.y, acc.y);
      acc.z = fmaf(xv.z, wv.z, acc.z);
      acc.w = fmaf(xv.w, wv.w, acc.w);
    }
    og[g * C4 + lane] = acc;                     // each float4 written exactly once
  }
}

extern "C" void kernel_launch(void* const* d_in, const int* in_sizes, int n_in,
                              void* d_out, int out_size, void* d_ws, size_t ws_size,
                              hipStream_t stream) {
  const float* x = (const float*)d_in[0];
  const float* w = (const float*)d_in[1];
  float* out = (float*)d_out;
  const int n_rows = in_sizes[0] / (NORD * 4 * C4);  // = 2048
  so2_kernel<<<n_rows, 256, 0, stream>>>(x, w, out);
}

// Round 3
// 215.050 us; speedup vs baseline: 1.3365x; 1.3365x over previous
//
#include <hip/hip_runtime.h>

// SO2Linear: out[n, M_out[e], c] += x[n, M_in[e], c] * weight[w_idx[e], c] * sign[e]
// L_MAX=6 -> 49 orders, 413 entries, 231 weights. N=2048, C=256.
// All metadata is a deterministic function of L_MAX -> constexpr, fully unrolled
// into immediates (no metadata loads on the critical path).

#define LMAX 6
#define NORD 49            // (LMAX+1)^2
#define NENT 413
#define C4   64            // C/4 float4 lanes
#define NW   8             // waves per block
#define BLK  512

struct Meta {
  unsigned packed[NENT];   // m_in | (w_idx<<8) | (sign_bit<<31), sorted by (i_out, i_in)
  int gstart[NORD + 1];    // entry range per i_out group
  int wbeg[NW + 1];        // group-range boundaries for the NW waves of a block
};

constexpr Meta make_meta() {
  Meta m{};
  int io[NENT] = {}, ii[NENT] = {}, wi[NENT] = {}, sg[NENT] = {};
  int cnt = 0, widx = 0;
  for (int lo = 0; lo <= LMAX; ++lo) {
    for (int li = 0; li <= LMAX; ++li) {
      int mn = lo < li ? lo : li;
      for (int mw = -mn; mw <= mn; ++mw) {
        if (mw == 0) {
          io[cnt] = lo * lo + lo; ii[cnt] = li * li + li;
          wi[cnt] = widx; sg[cnt] = 0; ++cnt;
        } else {
          int a = mw > 0 ? mw : -mw;
          io[cnt] = lo * lo + lo - a; ii[cnt] = li * li + li - mw;
          wi[cnt] = widx; sg[cnt] = 0; ++cnt;
          io[cnt] = lo * lo + lo + a; ii[cnt] = li * li + li + mw;
          wi[cnt] = widx; sg[cnt] = (mw < 0) ? 1 : 0; ++cnt;
        }
        ++widx;
      }
    }
  }
  // Sort by (i_out, i_in): keys unique -> bucket sort.
  int slot[NORD * NORD];
  for (int k = 0; k < NORD * NORD; ++k) slot[k] = -1;
  for (int e = 0; e < cnt; ++e) slot[io[e] * NORD + ii[e]] = e;
  int order[NENT] = {};
  int s = 0;
  for (int k = 0; k < NORD * NORD; ++k)
    if (slot[k] >= 0) order[s++] = slot[k];
  int gc[NORD] = {};
  for (int e = 0; e < cnt; ++e) gc[io[e]]++;
  m.gstart[0] = 0;
  for (int g = 0; g < NORD; ++g) m.gstart[g + 1] = m.gstart[g] + gc[g];
  for (int t = 0; t < cnt; ++t) {
    int e = order[t];
    m.packed[t] = (unsigned)ii[e] | ((unsigned)wi[e] << 8) | ((unsigned)sg[e] << 31);
  }
  // NW-way partition of the 49 groups, balanced by entry count.
  m.wbeg[0] = 0; m.wbeg[NW] = NORD;
  for (int y = 1; y < NW; ++y) {
    int target = (cnt * y) / NW;
    int g = m.wbeg[y - 1] + 1;
    while (g < NORD && m.gstart[g] < target) ++g;
    if (g - 1 > m.wbeg[y - 1] &&
        (m.gstart[g] - target) > (target - m.gstart[g - 1])) --g;
    int maxg = NORD - (NW - y);          // leave room for remaining waves
    if (g > maxg) g = maxg;
    m.wbeg[y] = g;
  }
  return m;
}

static constexpr Meta g_meta = make_meta();

// ---- fully-unrolled entry loop: all indices are immediates ----
template <int E, int E1>
struct Ent {
  __device__ static inline void run(float4& acc, const float4* __restrict__ xs,
                                    const float4* __restrict__ wg, int lane) {
    constexpr unsigned p = g_meta.packed[E];
    constexpr int mi = (int)(p & 255u);
    constexpr int wix = (int)((p >> 8) & 0x3FFu);
    constexpr bool neg = (p & 0x80000000u) != 0u;
    float4 xv = xs[mi * C4 + lane];        // ds_read_b128, conflict-free
    float4 wv = wg[wix * C4 + lane];       // global L2-hit, coalesced 1KB/wave
    if constexpr (neg) {
      acc.x = fmaf(-xv.x, wv.x, acc.x);
      acc.y = fmaf(-xv.y, wv.y, acc.y);
      acc.z = fmaf(-xv.z, wv.z, acc.z);
      acc.w = fmaf(-xv.w, wv.w, acc.w);
    } else {
      acc.x = fmaf(xv.x, wv.x, acc.x);
      acc.y = fmaf(xv.y, wv.y, acc.y);
      acc.z = fmaf(xv.z, wv.z, acc.z);
      acc.w = fmaf(xv.w, wv.w, acc.w);
    }
    Ent<E + 1, E1>::run(acc, xs, wg, lane);
  }
};
template <int E1>
struct Ent<E1, E1> {
  __device__ static inline void run(float4&, const float4*, const float4*, int) {}
};

template <int G, int G1>
struct Grp {
  __device__ static inline void run(const float4* __restrict__ xs,
                                    const float4* __restrict__ wg,
                                    float4* __restrict__ og, int lane) {
    float4 acc = make_float4(0.f, 0.f, 0.f, 0.f);
    Ent<g_meta.gstart[G], g_meta.gstart[G + 1]>::run(acc, xs, wg, lane);
    og[G * C4 + lane] = acc;               // each float4 written exactly once
    Grp<G + 1, G1>::run(xs, wg, og, lane);
  }
};
template <int G1>
struct Grp<G1, G1> {
  __device__ static inline void run(const float4*, const float4*, float4*, int) {}
};

__global__ __launch_bounds__(BLK, 4) void so2_kernel(
    const float* __restrict__ x, const float* __restrict__ w,
    float* __restrict__ out) {
  __shared__ float4 xs[NORD * C4];  // 50176 B
  const int tid = threadIdx.x;
  const int n = blockIdx.x;
  const int wv = tid >> 6;
  const int lane = tid & 63;

  // Stage x[n] into LDS via direct HBM->LDS DMA (16B/lane, linear dest).
  const float4* __restrict__ xg =
      reinterpret_cast<const float4*>(x) + (size_t)n * (NORD * C4);
#pragma unroll
  for (int i = 0; i < 7; ++i) {
    const int slot = i * BLK + wv * 64;    // wave-uniform float4 base
    if (slot < NORD * C4) {
      __builtin_amdgcn_global_load_lds(
          (const __attribute__((address_space(1))) void*)(xg + slot + lane),
          (__attribute__((address_space(3))) void*)(&xs[slot]), 16, 0, 0);
    }
  }
  __syncthreads();  // drains vmcnt (incl. global_load_lds) before LDS reads

  const float4* __restrict__ wg = reinterpret_cast<const float4*>(w);
  float4* __restrict__ og =
      reinterpret_cast<float4*>(out) + (size_t)n * (NORD * C4);

  switch (wv) {
    case 0: Grp<g_meta.wbeg[0], g_meta.wbeg[1]>::run(xs, wg, og, lane); break;
    case 1: Grp<g_meta.wbeg[1], g_meta.wbeg[2]>::run(xs, wg, og, lane); break;
    case 2: Grp<g_meta.wbeg[2], g_meta.wbeg[3]>::run(xs, wg, og, lane); break;
    case 3: Grp<g_meta.wbeg[3], g_meta.wbeg[4]>::run(xs, wg, og, lane); break;
    case 4: Grp<g_meta.wbeg[4], g_meta.wbeg[5]>::run(xs, wg, og, lane); break;
    case 5: Grp<g_meta.wbeg[5], g_meta.wbeg[6]>::run(xs, wg, og, lane); break;
    case 6: Grp<g_meta.wbeg[6], g_meta.wbeg[7]>::run(xs, wg, og, lane); break;
    case 7: Grp<g_meta.wbeg[7], g_meta.wbeg[8]>::run(xs, wg, og, lane); break;
  }
}

extern "C" void kernel_launch(void* const* d_in, const int* in_sizes, int n_in,
                              void* d_out, int out_size, void* d_ws, size_t ws_size,
                              hipStream_t stream) {
  const float* x = (const float*)d_in[0];
  const float* w = (const float*)d_in[1];
  float* out = (float*)d_out;
  const int n_rows = in_sizes[0] / (NORD * 4 * C4);  // = 2048
  so2_kernel<<<n_rows, BLK, 0, stream>>>(x, w, out);
}